// Round 1
// 2103.810 us; speedup vs baseline: 1.1485x; 1.1485x over previous
//
#include <hip/hip_runtime.h>
#include <stdint.h>

// Problem constants
#define BB   64
#define TT   512
#define DIN  512
#define HH   1024
#define DOUT 512

// 4 independent batch groups x 16 rows; per group 16 WGs each owning 64 cols;
// 8 waves/WG K-split (128 K each; keeps weight frags <= 128 VGPR, no spills).
// Layer 1 runs concurrently (WGs 64..127), consuming h1seq per-step.
//
// SYNC: NO flags. Producers store h as bf16 pairs (one dword per thread, sc1).
// Consumers spin on the DATA with a NaN sentinel: the tanh epilogue
// (hv = 1 - 2/(e+1), e >= 0 finite or +inf) always yields finite |hv| <= 1,
// so f2bf never emits 0x7FFF. 0x7FFF7FFF is therefore unreachable in any
// stored dword. State buffers are poisoned with the sentinel every launch
// (poison_kernel), every location is written exactly once, dword stores are
// atomic -> a non-sentinel poll result IS the valid data (1 LLC round trip
// replaces drain+flag-store+flag-poll+data-load).
#define GROUPS        4
#define ROWS          16
#define WGS_PER_GROUP 16
#define NSLICE        64
#define THREADS       512
#define NW            8
#define PSTR          18            // LDS parts stride: 18 floats -> uniform
                                    // 2-way banking (free); 17 was 4-way
#define SENT          0x7fff7fffu   // two NaN bf16 halves; unreachable output

typedef __attribute__((ext_vector_type(8))) short frag8;        // 8 x bf16
typedef __attribute__((ext_vector_type(4))) float f32x4;        // MFMA acc
typedef __attribute__((ext_vector_type(4))) unsigned int u32x4; // asm payload

union U4F8 { u32x4 u; frag8 f; };

__device__ __forceinline__ float bf2f(unsigned short u) {
  union { unsigned int i; float f; } v; v.i = ((unsigned int)u) << 16; return v.f;
}
__device__ __forceinline__ unsigned short f2bf(float f) {
  union { float f; unsigned int i; } v; v.f = f;
  unsigned int x = v.i;
  x += 0x7fffu + ((x >> 16) & 1u);   // RNE
  return (unsigned short)(x >> 16);
}
__device__ __forceinline__ frag8 ld8f32(const float* p) {
  frag8 r;
#pragma unroll
  for (int j = 0; j < 8; ++j) r[j] = (short)f2bf(p[j]);
  return r;
}

// ---- batched device-scope (sc1) polling loads: issue all, ONE waitcnt,
// sentinel-check every dword. Values are write-once, so a lane whose words
// were already valid on an earlier iteration just reloads identical data.
// NOTE: "=&v" early-clobber is REQUIRED — outputs are written by the first
// load while the pointer input is still needed by the later ones.
__device__ __forceinline__ bool ldx4_poll(frag8 a[4], const unsigned short* p) {
  u32x4 t0, t1, t2, t3;
  asm volatile(
      "global_load_dwordx4 %0, %4, off sc1\n\t"
      "global_load_dwordx4 %1, %4, off offset:64 sc1\n\t"
      "global_load_dwordx4 %2, %4, off offset:128 sc1\n\t"
      "global_load_dwordx4 %3, %4, off offset:192 sc1\n\t"
      "s_waitcnt vmcnt(0)"
      : "=&v"(t0), "=&v"(t1), "=&v"(t2), "=&v"(t3)
      : "v"(p)
      : "memory");
  bool ok = (t0[0] != SENT) & (t0[1] != SENT) & (t0[2] != SENT) & (t0[3] != SENT)
          & (t1[0] != SENT) & (t1[1] != SENT) & (t1[2] != SENT) & (t1[3] != SENT)
          & (t2[0] != SENT) & (t2[1] != SENT) & (t2[2] != SENT) & (t2[3] != SENT)
          & (t3[0] != SENT) & (t3[1] != SENT) & (t3[2] != SENT) & (t3[3] != SENT);
  U4F8 u;
  u.u = t0; a[0] = u.f;  u.u = t1; a[1] = u.f;
  u.u = t2; a[2] = u.f;  u.u = t3; a[3] = u.f;
  return __ballot(ok) == ~0ull;
}
__device__ __forceinline__ bool ldx8_poll(frag8 a[4], frag8 b[4],
                                          const unsigned short* pa,
                                          const unsigned short* pb) {
  u32x4 t0, t1, t2, t3, s0, s1, s2, s3;
  asm volatile(
      "global_load_dwordx4 %0, %8, off sc1\n\t"
      "global_load_dwordx4 %1, %8, off offset:64 sc1\n\t"
      "global_load_dwordx4 %2, %8, off offset:128 sc1\n\t"
      "global_load_dwordx4 %3, %8, off offset:192 sc1\n\t"
      "global_load_dwordx4 %4, %9, off sc1\n\t"
      "global_load_dwordx4 %5, %9, off offset:64 sc1\n\t"
      "global_load_dwordx4 %6, %9, off offset:128 sc1\n\t"
      "global_load_dwordx4 %7, %9, off offset:192 sc1\n\t"
      "s_waitcnt vmcnt(0)"
      : "=&v"(t0), "=&v"(t1), "=&v"(t2), "=&v"(t3),
        "=&v"(s0), "=&v"(s1), "=&v"(s2), "=&v"(s3)
      : "v"(pa), "v"(pb)
      : "memory");
  bool ok = (t0[0] != SENT) & (t0[1] != SENT) & (t0[2] != SENT) & (t0[3] != SENT)
          & (t1[0] != SENT) & (t1[1] != SENT) & (t1[2] != SENT) & (t1[3] != SENT)
          & (t2[0] != SENT) & (t2[1] != SENT) & (t2[2] != SENT) & (t2[3] != SENT)
          & (t3[0] != SENT) & (t3[1] != SENT) & (t3[2] != SENT) & (t3[3] != SENT)
          & (s0[0] != SENT) & (s0[1] != SENT) & (s0[2] != SENT) & (s0[3] != SENT)
          & (s1[0] != SENT) & (s1[1] != SENT) & (s1[2] != SENT) & (s1[3] != SENT)
          & (s2[0] != SENT) & (s2[1] != SENT) & (s2[2] != SENT) & (s2[3] != SENT)
          & (s3[0] != SENT) & (s3[1] != SENT) & (s3[2] != SENT) & (s3[3] != SENT);
  U4F8 u;
  u.u = t0; a[0] = u.f;  u.u = t1; a[1] = u.f;
  u.u = t2; a[2] = u.f;  u.u = t3; a[3] = u.f;
  u.u = s0; b[0] = u.f;  u.u = s1; b[1] = u.f;
  u.u = s2; b[2] = u.f;  u.u = s3; b[3] = u.f;
  return __ballot(ok) == ~0ull;
}
__device__ __forceinline__ void st32_sc1(unsigned int* p, unsigned int v) {
  asm volatile("global_store_dword %0, %1, off sc1" :: "v"(p), "v"(v) : "memory");
}

// One RNN layer scan step-loop. L0: X = fp32 x, state seq = h1seq.
// L1: X = bf16 h1seq (sentinel-polled), state seq = h2seq.
// S layout: [row][t][HH] bf16, write-once per location.
template<int KIN, bool L0>
__device__ void scan_body(const void* Xv,
                          const float* Wih, const float* Whh,
                          const float* bih, const float* bhh,
                          unsigned short* S,
                          int g, int s, float* parts)
{
  constexpr int KIT_IN = KIN / (NW * 32);   // L0: 2, L1: 4
  constexpr int KIT_HH = HH  / (NW * 32);   // 4

  const int j0  = s * NSLICE;
  const int r0  = g * ROWS;
  const int tid = threadIdx.x;
  const int w   = tid >> 6;                 // wave 0..7 (K-split)
  const int l   = tid & 63;
  const int lm  = l & 15;
  const int lq  = l >> 4;

  // ---- preload weights to VGPR frags (fp32 -> bf16 once) ----
  // B-frag: lane holds W[n = j0+nt*16+lm][k = w*(K/8) + kit*32 + lq*8 .. +7]
  frag8 wih_f[KIT_IN][4];
  frag8 whh_f[KIT_HH][4];
#pragma unroll
  for (int kit = 0; kit < KIT_IN; ++kit)
#pragma unroll
    for (int nt = 0; nt < 4; ++nt) {
      int n = j0 + nt * 16 + lm;
      int k = w * (KIN / NW) + kit * 32 + lq * 8;
      wih_f[kit][nt] = ld8f32(Wih + (size_t)n * KIN + k);
    }
#pragma unroll
  for (int kit = 0; kit < KIT_HH; ++kit)
#pragma unroll
    for (int nt = 0; nt < 4; ++nt) {
      int n = j0 + nt * 16 + lm;
      int k = w * (HH / NW) + kit * 32 + lq * 8;
      whh_f[kit][nt] = ld8f32(Whh + (size_t)n * HH + k);
    }

  // epilogue: thread -> (row = tid&15, 2 contiguous cols at (tid>>4)*2)
  const int erow = tid & 15;
  const int ecg  = tid >> 4;               // 0..31
  float bias2[2];
#pragma unroll
  for (int j = 0; j < 2; ++j) {
    int c = j0 + ecg * 2 + j;
    bias2[j] = bih[c] + bhh[c];
  }

  for (int t = 0; t < TT; ++t) {
    f32x4 acc[4];
#pragma unroll
    for (int nt = 0; nt < 4; ++nt) acc[nt] = (f32x4){0.f, 0.f, 0.f, 0.f};

    if constexpr (L0) {
      // x-projection FIRST (independent of h): executes while peers finish
      const float* xr = (const float*)Xv
          + ((size_t)(r0 + lm) * TT + t) * KIN + w * (KIN / NW) + lq * 8;
#pragma unroll
      for (int kit = 0; kit < KIT_IN; ++kit) {
        float4 x0 = *(const float4*)(xr + kit * 32);
        float4 x1 = *(const float4*)(xr + kit * 32 + 4);
        frag8 a;
        a[0] = (short)f2bf(x0.x); a[1] = (short)f2bf(x0.y);
        a[2] = (short)f2bf(x0.z); a[3] = (short)f2bf(x0.w);
        a[4] = (short)f2bf(x1.x); a[5] = (short)f2bf(x1.y);
        a[6] = (short)f2bf(x1.z); a[7] = (short)f2bf(x1.w);
#pragma unroll
        for (int nt = 0; nt < 4; ++nt)
          acc[nt] = __builtin_amdgcn_mfma_f32_16x16x32_bf16(a, wih_f[kit][nt], acc[nt], 0, 0, 0);
      }
      if (t > 0) {   // recurrence: sentinel-poll h1seq[t-1] directly
        const unsigned short* ph = S + ((size_t)(r0 + lm) * TT + (t - 1)) * HH
                                     + w * (HH / NW) + lq * 8;
        frag8 hf[KIT_HH];
        while (!ldx4_poll(hf, ph)) {}
#pragma unroll
        for (int kit = 0; kit < KIT_HH; ++kit)
#pragma unroll
          for (int nt = 0; nt < 4; ++nt)
            acc[nt] = __builtin_amdgcn_mfma_f32_16x16x32_bf16(hf[kit], whh_f[kit][nt], acc[nt], 0, 0, 0);
      }
    } else {
      const unsigned short* px = (const unsigned short*)Xv
          + ((size_t)(r0 + lm) * TT + t) * KIN + w * (KIN / NW) + lq * 8;
      if (t > 0) {
        const unsigned short* ph = S + ((size_t)(r0 + lm) * TT + (t - 1)) * HH
                                     + w * (HH / NW) + lq * 8;
        frag8 xf[KIT_IN], hf[KIT_HH];
        while (!ldx8_poll(xf, hf, px, ph)) {}   // both gates, ONE round trip
#pragma unroll
        for (int kit = 0; kit < KIT_IN; ++kit)
#pragma unroll
          for (int nt = 0; nt < 4; ++nt)
            acc[nt] = __builtin_amdgcn_mfma_f32_16x16x32_bf16(xf[kit], wih_f[kit][nt], acc[nt], 0, 0, 0);
#pragma unroll
        for (int kit = 0; kit < KIT_HH; ++kit)
#pragma unroll
          for (int nt = 0; nt < 4; ++nt)
            acc[nt] = __builtin_amdgcn_mfma_f32_16x16x32_bf16(hf[kit], whh_f[kit][nt], acc[nt], 0, 0, 0);
      } else {
        frag8 xf[KIT_IN];
        while (!ldx4_poll(xf, px)) {}
#pragma unroll
        for (int kit = 0; kit < KIT_IN; ++kit)
#pragma unroll
          for (int nt = 0; nt < 4; ++nt)
            acc[nt] = __builtin_amdgcn_mfma_f32_16x16x32_bf16(xf[kit], wih_f[kit][nt], acc[nt], 0, 0, 0);
      }
    }

    // ---- pass1: K-split partials to LDS ----
    // C/D layout: col = lane&15, row = (lane>>4)*4 + reg  [verified m89/m91]
    // stride 18: lq*72%32 = {0,8,16,24} + lm -> uniform 2-way (free, m136)
#pragma unroll
    for (int nt = 0; nt < 4; ++nt)
#pragma unroll
      for (int r = 0; r < 4; ++r)
        parts[((w * 4 + nt) * 16 + lq * 4 + r) * PSTR + lm] = acc[nt][r];
    __syncthreads();

    // ---- pass2: reduce 8 K-chunks, tanh, pack 2 cols -> one dword sc1 store
    unsigned int hb2 = 0;
#pragma unroll
    for (int j = 0; j < 2; ++j) {
      int c  = ecg * 2 + j;
      int nt = c >> 4;
      int lc = c & 15;
      float sm = 0.f;
#pragma unroll
      for (int w8 = 0; w8 < NW; ++w8)
        sm += parts[((w8 * 4 + nt) * 16 + erow) * PSTR + lc];
      float u = sm + bias2[j];
      float e = __expf(2.0f * u);               // tanh via exp, inf-safe:
      float hv = 1.0f - 2.0f / (e + 1.0f);      // finite, |hv|<=1, NEVER NaN
      hb2 |= (unsigned int)f2bf(hv) << (16 * j);
    }
    unsigned short* dst = S + ((size_t)(r0 + erow) * TT + t) * HH + j0 + ecg * 2;
    st32_sc1((unsigned int*)dst, hb2);   // the store IS the publish
    __syncthreads();                     // guards LDS `parts` reuse only
  }
}

__global__ __launch_bounds__(THREADS, 1)
void rnn_fused(const float* x,
               const float* Wih0, const float* Whh0, const float* bih0, const float* bhh0,
               const float* Wih1, const float* Whh1, const float* bih1, const float* bhh1,
               unsigned short* h1seq, unsigned short* h2seq)
{
  __shared__ float parts[NW * 4 * 16 * PSTR];
  const int wg = blockIdx.x;
  if (wg < GROUPS * WGS_PER_GROUP) {
    const int g = wg / WGS_PER_GROUP, s = wg % WGS_PER_GROUP;
    scan_body<DIN, true>(x, Wih0, Whh0, bih0, bhh0, h1seq, g, s, parts);
  } else {
    const int wg2 = wg - GROUPS * WGS_PER_GROUP;
    const int g = wg2 / WGS_PER_GROUP, s = wg2 % WGS_PER_GROUP;
    scan_body<HH, false>(h1seq, Wih1, Whh1, bih1, bhh1, h2seq, g, s, parts);
  }
}

// poison h1seq+h2seq with the sentinel every launch (stale non-sentinel data
// from a previous launch would be a false-positive for the data-poll).
__global__ void poison_kernel(uint4* __restrict__ p, int n4) {
  int i  = blockIdx.x * blockDim.x + threadIdx.x;
  int st = gridDim.x * blockDim.x;
  const uint4 v = make_uint4(SENT, SENT, SENT, SENT);
  for (; i < n4; i += st) p[i] = v;
}

// out[m][n] = h2seq[m][T-1] . Wfc[n] + bfc[n]
__global__ void fc_kernel(const unsigned short* __restrict__ h2seq,  // bf16
                          const float* __restrict__ Wfc,             // fp32
                          const float* __restrict__ bfc,             // fp32
                          float* __restrict__ out)                   // fp32
{
  int idx = blockIdx.x * blockDim.x + threadIdx.x;  // 32768 = 64*512
  int m = idx >> 9;
  int n = idx & 511;
  const unsigned short* hp = h2seq + ((size_t)m * TT + (TT - 1)) * HH;
  const float*          wp = Wfc + (size_t)n * HH;
  float acc = 0.f;
#pragma unroll 4
  for (int k = 0; k < HH; k += 4) {
    ushort4 hv = *(const ushort4*)(hp + k);
    float4  wv = *(const float4*)(wp + k);
    acc += bf2f(hv.x) * wv.x + bf2f(hv.y) * wv.y
         + bf2f(hv.z) * wv.z + bf2f(hv.w) * wv.w;
  }
  out[idx] = acc + bfc[n];
}

extern "C" void kernel_launch(void* const* d_in, const int* in_sizes, int n_in,
                              void* d_out, int out_size, void* d_ws, size_t ws_size,
                              hipStream_t stream)
{
  const float* x    = (const float*)d_in[0];
  const float* Wih0 = (const float*)d_in[1];
  const float* Whh0 = (const float*)d_in[2];
  const float* bih0 = (const float*)d_in[3];
  const float* bhh0 = (const float*)d_in[4];
  const float* Wih1 = (const float*)d_in[5];
  const float* Whh1 = (const float*)d_in[6];
  const float* bih1 = (const float*)d_in[7];
  const float* bhh1 = (const float*)d_in[8];
  const float* Wfc  = (const float*)d_in[9];
  const float* bfc  = (const float*)d_in[10];

  // ws: h1seq (64MB) | h2seq (64MB) — both write-once bf16 [B][T][H]
  unsigned char* ws = (unsigned char*)d_ws;
  unsigned short* h1seq = (unsigned short*)ws;
  unsigned short* h2seq = (unsigned short*)(ws + (size_t)BB * TT * HH * 2);

  // sentinel-poison both state arrays (128 MiB, ~25 us)
  poison_kernel<<<4096, 256, 0, stream>>>(
      (uint4*)ws, (int)(((size_t)BB * TT * HH * 2 * 2) / 16));

  // fused 2-layer pipelined scan: WGs 0..63 = layer 0, 64..127 = layer 1
  rnn_fused<<<2 * GROUPS * WGS_PER_GROUP, THREADS, 0, stream>>>(
      x, Wih0, Whh0, bih0, bhh0, Wih1, Whh1, bih1, bhh1, h1seq, h2seq);

  fc_kernel<<<(BB * DOUT) / 256, 256, 0, stream>>>(h2seq, Wfc, bfc, (float*)d_out);
}

// Round 3
// 1960.467 us; speedup vs baseline: 1.2325x; 1.0731x over previous
//
#include <hip/hip_runtime.h>
#include <stdint.h>

// Problem constants
#define BB   64
#define TT   512
#define DIN  512
#define HH   1024
#define DOUT 512

// 4 independent batch groups x 16 rows; per group 16 WGs each owning 64 cols;
// 8 waves/WG K-split (128 K each). Layer 1 runs concurrently (WGs 64..127).
//
// SYNC: data-is-the-flag. Producers store h as bf16 pairs (one dword per
// thread, sc1). Consumers spin on the DATA with a NaN sentinel: tanh output
// is finite |h|<=1, so f2bf never emits 0x7FFF; 0x7FFF7FFF is unreachable.
// State buffers are sentinel-poisoned each launch; every location is written
// exactly once; dword stores are atomic -> non-sentinel poll result IS data.
//
// POLLS ARE FUSED (issue + s_waitcnt in ONE asm block). Round-2 lesson:
// split-phase polling (loads in flight across compiler-visible code) is
// UNSAFE — the allocator may spill/copy the in-flight destination registers
// before the data lands. Never split issue/wait across C++ code.
//
// This round: (a) L0 prefetches x(t+1) into registers during step t (x HBM
// latency off the per-step chain; step head is register-only), (b) L1
// tail-polls x(t+1)=h1[t+1] after its store (L0 runs ahead, so this is
// usually immediate) and polls own h2(t-1) only AFTER the x-MFMAs — more
// visibility time elapsed, post-detect tail halved, (c) double-buffered
// LDS `parts` -> ONE barrier per step (reuse at t+2 is ordered by the
// step-t poll: poll success implies all sibling waves stored h(t), which
// is after their pass2 reads).
#define GROUPS        4
#define ROWS          16
#define WGS_PER_GROUP 16
#define NSLICE        64
#define THREADS       512
#define NW            8
#define PSTR          18            // LDS parts stride: uniform 2-way (free)
#define PBUF          (NW * 4 * 16 * PSTR)
#define SENT          0x7fff7fffu   // two NaN bf16 halves; unreachable output

typedef __attribute__((ext_vector_type(8))) short frag8;        // 8 x bf16
typedef __attribute__((ext_vector_type(4))) float f32x4;        // MFMA acc
typedef __attribute__((ext_vector_type(4))) unsigned int u32x4; // asm payload

union U4F8 { u32x4 u; frag8 f; };

__device__ __forceinline__ float bf2f(unsigned short u) {
  union { unsigned int i; float f; } v; v.i = ((unsigned int)u) << 16; return v.f;
}
__device__ __forceinline__ unsigned short f2bf(float f) {
  union { float f; unsigned int i; } v; v.f = f;
  unsigned int x = v.i;
  x += 0x7fffu + ((x >> 16) & 1u);   // RNE
  return (unsigned short)(x >> 16);
}
__device__ __forceinline__ frag8 ld8f32(const float* p) {
  frag8 r;
#pragma unroll
  for (int j = 0; j < 8; ++j) r[j] = (short)f2bf(p[j]);
  return r;
}

// ---- fused device-scope (sc1) polling load: issue 4 dwordx4 + ONE waitcnt
// inside a single asm block (outputs are defined by the same asm that
// waits — no in-flight registers ever cross compiler-visible code).
// "=&v" early-clobber REQUIRED (outputs written while address still live).
__device__ __forceinline__ bool ldx4_poll(frag8 a[4], const unsigned short* p) {
  u32x4 t0, t1, t2, t3;
  asm volatile(
      "global_load_dwordx4 %0, %4, off sc1\n\t"
      "global_load_dwordx4 %1, %4, off offset:64 sc1\n\t"
      "global_load_dwordx4 %2, %4, off offset:128 sc1\n\t"
      "global_load_dwordx4 %3, %4, off offset:192 sc1\n\t"
      "s_waitcnt vmcnt(0)"
      : "=&v"(t0), "=&v"(t1), "=&v"(t2), "=&v"(t3)
      : "v"(p)
      : "memory");
  bool ok = (t0[0] != SENT) & (t0[1] != SENT) & (t0[2] != SENT) & (t0[3] != SENT)
          & (t1[0] != SENT) & (t1[1] != SENT) & (t1[2] != SENT) & (t1[3] != SENT)
          & (t2[0] != SENT) & (t2[1] != SENT) & (t2[2] != SENT) & (t2[3] != SENT)
          & (t3[0] != SENT) & (t3[1] != SENT) & (t3[2] != SENT) & (t3[3] != SENT);
  U4F8 u;
  u.u = t0; a[0] = u.f;  u.u = t1; a[1] = u.f;
  u.u = t2; a[2] = u.f;  u.u = t3; a[3] = u.f;
  return __ballot(ok) == ~0ull;
}
__device__ __forceinline__ void st32_sc1(unsigned int* p, unsigned int v) {
  asm volatile("global_store_dword %0, %1, off sc1" :: "v"(p), "v"(v) : "memory");
}

// One RNN layer scan step-loop. L0: X = fp32 x (register-prefetched),
// state seq = h1seq. L1: X = bf16 h1seq (tail-polled), state seq = h2seq.
// S layout: [row][t][HH] bf16, write-once per location.
template<int KIN, bool L0>
__device__ void scan_body(const void* Xv,
                          const float* Wih, const float* Whh,
                          const float* bih, const float* bhh,
                          unsigned short* S,
                          int g, int s, float* parts)
{
  constexpr int KIT_IN = KIN / (NW * 32);   // L0: 2, L1: 4
  constexpr int KIT_HH = HH  / (NW * 32);   // 4

  const int j0  = s * NSLICE;
  const int r0  = g * ROWS;
  const int tid = threadIdx.x;
  const int w   = tid >> 6;                 // wave 0..7 (K-split)
  const int l   = tid & 63;
  const int lm  = l & 15;
  const int lq  = l >> 4;

  // ---- preload weights to VGPR frags (fp32 -> bf16 once) ----
  // B-frag: lane holds W[n = j0+nt*16+lm][k = w*(K/8) + kit*32 + lq*8 .. +7]
  frag8 wih_f[KIT_IN][4];
  frag8 whh_f[KIT_HH][4];
#pragma unroll
  for (int kit = 0; kit < KIT_IN; ++kit)
#pragma unroll
    for (int nt = 0; nt < 4; ++nt) {
      int n = j0 + nt * 16 + lm;
      int k = w * (KIN / NW) + kit * 32 + lq * 8;
      wih_f[kit][nt] = ld8f32(Wih + (size_t)n * KIN + k);
    }
#pragma unroll
  for (int kit = 0; kit < KIT_HH; ++kit)
#pragma unroll
    for (int nt = 0; nt < 4; ++nt) {
      int n = j0 + nt * 16 + lm;
      int k = w * (HH / NW) + kit * 32 + lq * 8;
      whh_f[kit][nt] = ld8f32(Whh + (size_t)n * HH + k);
    }

  // epilogue: thread -> (row = tid&15, 2 contiguous cols at (tid>>4)*2)
  const int erow = tid & 15;
  const int ecg  = tid >> 4;               // 0..31
  float bias2[2];
#pragma unroll
  for (int j = 0; j < 2; ++j) {
    int c = j0 + ecg * 2 + j;
    bias2[j] = bih[c] + bhh[c];
  }

  // per-lane A-frag source offset within a timestep row
  const size_t koff = (size_t)w * (KIN / NW) + (size_t)lq * 8;

  // ---- stage x(0) into registers ----
  float4 xa[2 * KIT_IN];                    // L0 fp32 prefetch
  frag8  xf[KIT_IN];                        // L1 polled bf16 frags
  if constexpr (L0) {
    const float* xr = (const float*)Xv + ((size_t)(r0 + lm) * TT + 0) * KIN + koff;
#pragma unroll
    for (int kit = 0; kit < KIT_IN; ++kit) {
      xa[2 * kit]     = *(const float4*)(xr + kit * 32);
      xa[2 * kit + 1] = *(const float4*)(xr + kit * 32 + 4);
    }
  } else {
    const unsigned short* px = (const unsigned short*)Xv
        + ((size_t)(r0 + lm) * TT + 0) * KIN + koff;
    while (!ldx4_poll(xf, px)) {}
  }

  for (int t = 0; t < TT; ++t) {
    f32x4 acc[4];
#pragma unroll
    for (int nt = 0; nt < 4; ++nt) acc[nt] = (f32x4){0.f, 0.f, 0.f, 0.f};

    // ---- 1) x-projection: register-only at step head ----
    if constexpr (L0) {
#pragma unroll
      for (int kit = 0; kit < KIT_IN; ++kit) {
        const float* f0 = (const float*)&xa[2 * kit];
        const float* f1 = (const float*)&xa[2 * kit + 1];
        frag8 a;
#pragma unroll
        for (int j = 0; j < 4; ++j) {
          a[j]     = (short)f2bf(f0[j]);
          a[4 + j] = (short)f2bf(f1[j]);
        }
#pragma unroll
        for (int nt = 0; nt < 4; ++nt)
          acc[nt] = __builtin_amdgcn_mfma_f32_16x16x32_bf16(a, wih_f[kit][nt], acc[nt], 0, 0, 0);
      }
    } else {
#pragma unroll
      for (int kit = 0; kit < KIT_IN; ++kit)
#pragma unroll
        for (int nt = 0; nt < 4; ++nt)
          acc[nt] = __builtin_amdgcn_mfma_f32_16x16x32_bf16(xf[kit], wih_f[kit][nt], acc[nt], 0, 0, 0);
    }

    // ---- 2) own-state poll + recurrence MFMAs ----
    if (t > 0) {
      const unsigned short* ph = S + ((size_t)(r0 + lm) * TT + (t - 1)) * HH
                                   + (size_t)w * (HH / NW) + lq * 8;
      frag8 hf[KIT_HH];
      while (!ldx4_poll(hf, ph)) {}
      if constexpr (L0) {                   // prefetch x(t+1): latency hides
        if (t + 1 < TT) {                   // under h-MFMAs + reduce
          const float* xr = (const float*)Xv
              + ((size_t)(r0 + lm) * TT + (t + 1)) * KIN + koff;
#pragma unroll
          for (int kit = 0; kit < KIT_IN; ++kit) {
            xa[2 * kit]     = *(const float4*)(xr + kit * 32);
            xa[2 * kit + 1] = *(const float4*)(xr + kit * 32 + 4);
          }
        }
      }
#pragma unroll
      for (int kit = 0; kit < KIT_HH; ++kit)
#pragma unroll
        for (int nt = 0; nt < 4; ++nt)
          acc[nt] = __builtin_amdgcn_mfma_f32_16x16x32_bf16(hf[kit], whh_f[kit][nt], acc[nt], 0, 0, 0);
    } else if constexpr (L0) {              // t=0: prefetch x(1)
      const float* xr = (const float*)Xv + ((size_t)(r0 + lm) * TT + 1) * KIN + koff;
#pragma unroll
      for (int kit = 0; kit < KIT_IN; ++kit) {
        xa[2 * kit]     = *(const float4*)(xr + kit * 32);
        xa[2 * kit + 1] = *(const float4*)(xr + kit * 32 + 4);
      }
    }

    // ---- 3) pass1: K-split partials to LDS (double-buffered) ----
    // C/D layout: col = lane&15, row = (lane>>4)*4 + reg  [verified m89/m91]
    // stride 18: banks lm + {0,8,16,24} -> uniform 2-way (free, m136)
    float* pb = parts + (t & 1) * PBUF;
#pragma unroll
    for (int nt = 0; nt < 4; ++nt)
#pragma unroll
      for (int r = 0; r < 4; ++r)
        pb[((w * 4 + nt) * 16 + lq * 4 + r) * PSTR + lm] = acc[nt][r];
    __syncthreads();                        // the ONLY barrier per step

    // ---- pass2: reduce 8 K-chunks, tanh, pack 2 cols -> one dword sc1 store
    unsigned int hb2 = 0;
#pragma unroll
    for (int j = 0; j < 2; ++j) {
      int c  = ecg * 2 + j;
      int nt = c >> 4;
      int lc = c & 15;
      float sm = 0.f;
#pragma unroll
      for (int w8 = 0; w8 < NW; ++w8)
        sm += pb[((w8 * 4 + nt) * 16 + erow) * PSTR + lc];
      float u = sm + bias2[j];
      float e = __expf(2.0f * u);               // tanh via exp, inf-safe:
      float hv = 1.0f - 2.0f / (e + 1.0f);      // finite, |hv|<=1, NEVER NaN
      hb2 |= (unsigned int)f2bf(hv) << (16 * j);
    }
    unsigned short* dst = S + ((size_t)(r0 + erow) * TT + t) * HH + j0 + ecg * 2;
    st32_sc1((unsigned int*)dst, hb2);   // the store IS the publish
    // NO end barrier: parts[t&1] reuse at t+2 is ordered by the step-(t+1)
    // poll (its success implies every sibling wave finished pass2 of t+1's
    // predecessor and stored — reads of parts[t&1] are long done).

    // ---- 4) L1: tail-poll x(t+1) = h1[t+1] (L0 runs ahead; usually ready)
    if constexpr (!L0) {
      if (t + 1 < TT) {
        const unsigned short* px = (const unsigned short*)Xv
            + ((size_t)(r0 + lm) * TT + (t + 1)) * KIN + koff;
        while (!ldx4_poll(xf, px)) {}
      }
    }
  }
}

__global__ __launch_bounds__(THREADS, 1)
void rnn_fused(const float* x,
               const float* Wih0, const float* Whh0, const float* bih0, const float* bhh0,
               const float* Wih1, const float* Whh1, const float* bih1, const float* bhh1,
               unsigned short* h1seq, unsigned short* h2seq)
{
  __shared__ float parts[2 * PBUF];
  const int wg = blockIdx.x;
  if (wg < GROUPS * WGS_PER_GROUP) {
    const int g = wg / WGS_PER_GROUP, s = wg % WGS_PER_GROUP;
    scan_body<DIN, true>(x, Wih0, Whh0, bih0, bhh0, h1seq, g, s, parts);
  } else {
    const int wg2 = wg - GROUPS * WGS_PER_GROUP;
    const int g = wg2 / WGS_PER_GROUP, s = wg2 % WGS_PER_GROUP;
    scan_body<HH, false>(h1seq, Wih1, Whh1, bih1, bhh1, h2seq, g, s, parts);
  }
}

// poison h1seq+h2seq with the sentinel every launch (stale non-sentinel data
// from a previous launch would be a false-positive for the data-poll).
__global__ void poison_kernel(uint4* __restrict__ p, int n4) {
  int i  = blockIdx.x * blockDim.x + threadIdx.x;
  int st = gridDim.x * blockDim.x;
  const uint4 v = make_uint4(SENT, SENT, SENT, SENT);
  for (; i < n4; i += st) p[i] = v;
}

// out[m][n] = h2seq[m][T-1] . Wfc[n] + bfc[n]
__global__ void fc_kernel(const unsigned short* __restrict__ h2seq,  // bf16
                          const float* __restrict__ Wfc,             // fp32
                          const float* __restrict__ bfc,             // fp32
                          float* __restrict__ out)                   // fp32
{
  int idx = blockIdx.x * blockDim.x + threadIdx.x;  // 32768 = 64*512
  int m = idx >> 9;
  int n = idx & 511;
  const unsigned short* hp = h2seq + ((size_t)m * TT + (TT - 1)) * HH;
  const float*          wp = Wfc + (size_t)n * HH;
  float acc = 0.f;
#pragma unroll 4
  for (int k = 0; k < HH; k += 4) {
    ushort4 hv = *(const ushort4*)(hp + k);
    float4  wv = *(const float4*)(wp + k);
    acc += bf2f(hv.x) * wv.x + bf2f(hv.y) * wv.y
         + bf2f(hv.z) * wv.z + bf2f(hv.w) * wv.w;
  }
  out[idx] = acc + bfc[n];
}

extern "C" void kernel_launch(void* const* d_in, const int* in_sizes, int n_in,
                              void* d_out, int out_size, void* d_ws, size_t ws_size,
                              hipStream_t stream)
{
  const float* x    = (const float*)d_in[0];
  const float* Wih0 = (const float*)d_in[1];
  const float* Whh0 = (const float*)d_in[2];
  const float* bih0 = (const float*)d_in[3];
  const float* bhh0 = (const float*)d_in[4];
  const float* Wih1 = (const float*)d_in[5];
  const float* Whh1 = (const float*)d_in[6];
  const float* bih1 = (const float*)d_in[7];
  const float* bhh1 = (const float*)d_in[8];
  const float* Wfc  = (const float*)d_in[9];
  const float* bfc  = (const float*)d_in[10];

  // ws: h1seq (64MB) | h2seq (64MB) — both write-once bf16 [B][T][H]
  unsigned char* ws = (unsigned char*)d_ws;
  unsigned short* h1seq = (unsigned short*)ws;
  unsigned short* h2seq = (unsigned short*)(ws + (size_t)BB * TT * HH * 2);

  // sentinel-poison both state arrays (128 MiB, ~25 us)
  poison_kernel<<<4096, 256, 0, stream>>>(
      (uint4*)ws, (int)(((size_t)BB * TT * HH * 2 * 2) / 16));

  // fused 2-layer pipelined scan: WGs 0..63 = layer 0, 64..127 = layer 1
  rnn_fused<<<2 * GROUPS * WGS_PER_GROUP, THREADS, 0, stream>>>(
      x, Wih0, Whh0, bih0, bhh0, Wih1, Whh1, bih1, bhh1, h1seq, h2seq);

  fc_kernel<<<(BB * DOUT) / 256, 256, 0, stream>>>(h2seq, Wfc, bfc, (float*)d_out);
}

// Round 4
// 1859.185 us; speedup vs baseline: 1.2996x; 1.0545x over previous
//
#include <hip/hip_runtime.h>
#include <stdint.h>

// Problem constants
#define BB   64
#define TT   512
#define DIN  512
#define HH   1024
#define DOUT 512

// 4 independent batch groups x 16 rows; per group 16 WGs each owning 64 cols;
// 8 waves/WG K-split (128 K each). Layer 1 runs concurrently (WGs 64..127).
//
// SYNC: data-is-the-flag. Producers store h as bf16 (sc1). Consumers spin on
// the DATA with a NaN sentinel: tanh output is finite |h|<=1, so f2bf never
// emits 0x7FFF; 0x7FFF7FFF is unreachable. State buffers are sentinel-
// poisoned each launch; every location is written exactly once; dword stores
// are atomic -> non-sentinel poll result IS the data.
//
// POLLS ARE FUSED (issue + s_waitcnt in ONE asm block). Round-2 lesson:
// split-phase polling (asm-output loads in flight across compiler-visible
// code) is UNSAFE — the allocator may spill/copy the in-flight destination
// registers before data lands. (Compiler-managed prefetch loads in flight
// across our asm are fine — the compiler tracks its own loads.)
//
// Round-4 changes (congestion + exposed-latency attack):
//  (a) light-probe spin: full poll once, then 32B/lane probe (one chunk per
//      producer WG) until it passes, then full confirm — ~2x less spin
//      traffic on the coherent fabric -> lower RTT for everyone.
//  (b) L0 issues x(t+1) prefetch BEFORE the h-poll; the poll's vmcnt(0)
//      drains it -> prefetch latency rides entirely under the spin.
//  (c) publish via LDS stage + 128 dwordx4 sc1 stores (was 512 dword
//      stores) -> 4x fewer commit messages, shorter visibility tail.
#define GROUPS        4
#define ROWS          16
#define WGS_PER_GROUP 16
#define NSLICE        64
#define THREADS       512
#define NW            8
#define PSTR          18            // LDS parts stride: uniform 2-way (free)
#define PBUF          (NW * 4 * 16 * PSTR)
#define SSTR          36            // stage stride (dwords): 16B-aligned rows,
                                    // banks 4*(row+c8)+i -> ~2-way (free)
#define SENT          0x7fff7fffu   // two NaN bf16 halves; unreachable output

typedef __attribute__((ext_vector_type(8))) short frag8;        // 8 x bf16
typedef __attribute__((ext_vector_type(4))) float f32x4;        // MFMA acc
typedef __attribute__((ext_vector_type(4))) unsigned int u32x4; // asm payload

union U4F8 { u32x4 u; frag8 f; };

__device__ __forceinline__ float bf2f(unsigned short u) {
  union { unsigned int i; float f; } v; v.i = ((unsigned int)u) << 16; return v.f;
}
__device__ __forceinline__ unsigned short f2bf(float f) {
  union { float f; unsigned int i; } v; v.f = f;
  unsigned int x = v.i;
  x += 0x7fffu + ((x >> 16) & 1u);   // RNE
  return (unsigned short)(x >> 16);
}
__device__ __forceinline__ frag8 ld8f32(const float* p) {
  frag8 r;
#pragma unroll
  for (int j = 0; j < 8; ++j) r[j] = (short)f2bf(p[j]);
  return r;
}

// ---- fused device-scope (sc1) polling load: 4 dwordx4 + ONE waitcnt inside
// a single asm block. "=&v" early-clobber REQUIRED.
__device__ __forceinline__ bool ldx4_poll(frag8 a[4], const unsigned short* p) {
  u32x4 t0, t1, t2, t3;
  asm volatile(
      "global_load_dwordx4 %0, %4, off sc1\n\t"
      "global_load_dwordx4 %1, %4, off offset:64 sc1\n\t"
      "global_load_dwordx4 %2, %4, off offset:128 sc1\n\t"
      "global_load_dwordx4 %3, %4, off offset:192 sc1\n\t"
      "s_waitcnt vmcnt(0)"
      : "=&v"(t0), "=&v"(t1), "=&v"(t2), "=&v"(t3)
      : "v"(p)
      : "memory");
  bool ok = (t0[0] != SENT) & (t0[1] != SENT) & (t0[2] != SENT) & (t0[3] != SENT)
          & (t1[0] != SENT) & (t1[1] != SENT) & (t1[2] != SENT) & (t1[3] != SENT)
          & (t2[0] != SENT) & (t2[1] != SENT) & (t2[2] != SENT) & (t2[3] != SENT)
          & (t3[0] != SENT) & (t3[1] != SENT) & (t3[2] != SENT) & (t3[3] != SENT);
  U4F8 u;
  u.u = t0; a[0] = u.f;  u.u = t1; a[1] = u.f;
  u.u = t2; a[2] = u.f;  u.u = t3; a[3] = u.f;
  return __ballot(ok) == ~0ull;
}
// light probe: one dwordx4 from EACH producer WG's range (offsets 0, 128).
// 32B/lane instead of 64B — halves spin traffic; covers both producers so
// a straggling second producer cannot turn the spin into full-poll traffic.
__device__ __forceinline__ bool probe2(const unsigned short* p) {
  u32x4 a, b;
  asm volatile(
      "global_load_dwordx4 %0, %2, off sc1\n\t"
      "global_load_dwordx4 %1, %2, off offset:128 sc1\n\t"
      "s_waitcnt vmcnt(0)"
      : "=&v"(a), "=&v"(b)
      : "v"(p)
      : "memory");
  bool ok = (a[0] != SENT) & (a[1] != SENT) & (a[2] != SENT) & (a[3] != SENT)
          & (b[0] != SENT) & (b[1] != SENT) & (b[2] != SENT) & (b[3] != SENT);
  return __ballot(ok) == ~0ull;
}
// full-then-light polling: first attempt full (steady-state hit for tail
// polls); then light spin; confirm full before consuming.
__device__ __forceinline__ void poll256(frag8 a[4], const unsigned short* p) {
  if (ldx4_poll(a, p)) return;
  for (;;) {
    while (!probe2(p)) {}
    if (ldx4_poll(a, p)) return;
  }
}
__device__ __forceinline__ void st128_sc1(unsigned int* p, u32x4 v) {
  asm volatile("global_store_dwordx4 %0, %1, off sc1" :: "v"(p), "v"(v) : "memory");
}

// One RNN layer scan step-loop. L0: X = fp32 x (register-prefetched under
// the poll), state seq = h1seq. L1: X = bf16 h1seq (tail-polled), state
// seq = h2seq. S layout: [row][t][HH] bf16, write-once per location.
template<int KIN, bool L0>
__device__ void scan_body(const void* Xv,
                          const float* Wih, const float* Whh,
                          const float* bih, const float* bhh,
                          unsigned short* S,
                          int g, int s, float* parts, unsigned int* stage)
{
  constexpr int KIT_IN = KIN / (NW * 32);   // L0: 2, L1: 4
  constexpr int KIT_HH = HH  / (NW * 32);   // 4

  const int j0  = s * NSLICE;
  const int r0  = g * ROWS;
  const int tid = threadIdx.x;
  const int w   = tid >> 6;                 // wave 0..7 (K-split)
  const int l   = tid & 63;
  const int lm  = l & 15;
  const int lq  = l >> 4;

  // ---- preload weights to VGPR frags (fp32 -> bf16 once) ----
  // B-frag: lane holds W[n = j0+nt*16+lm][k = w*(K/8) + kit*32 + lq*8 .. +7]
  frag8 wih_f[KIT_IN][4];
  frag8 whh_f[KIT_HH][4];
#pragma unroll
  for (int kit = 0; kit < KIT_IN; ++kit)
#pragma unroll
    for (int nt = 0; nt < 4; ++nt) {
      int n = j0 + nt * 16 + lm;
      int k = w * (KIN / NW) + kit * 32 + lq * 8;
      wih_f[kit][nt] = ld8f32(Wih + (size_t)n * KIN + k);
    }
#pragma unroll
  for (int kit = 0; kit < KIT_HH; ++kit)
#pragma unroll
    for (int nt = 0; nt < 4; ++nt) {
      int n = j0 + nt * 16 + lm;
      int k = w * (HH / NW) + kit * 32 + lq * 8;
      whh_f[kit][nt] = ld8f32(Whh + (size_t)n * HH + k);
    }

  // pass2: thread -> (row = tid&15, 2 contiguous cols at (tid>>4)*2)
  const int erow = tid & 15;
  const int ecg  = tid >> 4;               // 0..31
  float bias2[2];
#pragma unroll
  for (int j = 0; j < 2; ++j) {
    int c = j0 + ecg * 2 + j;
    bias2[j] = bih[c] + bhh[c];
  }
  // publisher: thread < 128 -> (row = tid>>3, 8 cols at (tid&7)*8)
  const int prow = tid >> 3;
  const int pc8  = tid & 7;

  // per-lane A-frag source offset within a timestep row
  const size_t koff = (size_t)w * (KIN / NW) + (size_t)lq * 8;

  // ---- stage x(0) into registers ----
  float4 xa[2 * KIT_IN];                    // L0 fp32 prefetch
  frag8  xf[KIT_IN];                        // L1 polled bf16 frags
  if constexpr (L0) {
    const float* xr = (const float*)Xv + ((size_t)(r0 + lm) * TT + 0) * KIN + koff;
#pragma unroll
    for (int kit = 0; kit < KIT_IN; ++kit) {
      xa[2 * kit]     = *(const float4*)(xr + kit * 32);
      xa[2 * kit + 1] = *(const float4*)(xr + kit * 32 + 4);
    }
  } else {
    const unsigned short* px = (const unsigned short*)Xv
        + ((size_t)(r0 + lm) * TT + 0) * KIN + koff;
    poll256(xf, px);
  }

  for (int t = 0; t < TT; ++t) {
    f32x4 acc[4];
#pragma unroll
    for (int nt = 0; nt < 4; ++nt) acc[nt] = (f32x4){0.f, 0.f, 0.f, 0.f};

    // ---- 1) x-projection: register-only at step head ----
    if constexpr (L0) {
#pragma unroll
      for (int kit = 0; kit < KIT_IN; ++kit) {
        const float* f0 = (const float*)&xa[2 * kit];
        const float* f1 = (const float*)&xa[2 * kit + 1];
        frag8 a;
#pragma unroll
        for (int j = 0; j < 4; ++j) {
          a[j]     = (short)f2bf(f0[j]);
          a[4 + j] = (short)f2bf(f1[j]);
        }
#pragma unroll
        for (int nt = 0; nt < 4; ++nt)
          acc[nt] = __builtin_amdgcn_mfma_f32_16x16x32_bf16(a, wih_f[kit][nt], acc[nt], 0, 0, 0);
      }
      // ---- 2) issue x(t+1) prefetch BEFORE the poll: the poll's vmcnt(0)
      // drains it, so its HBM latency rides entirely under the spin.
      if (t + 1 < TT) {
        const float* xr = (const float*)Xv
            + ((size_t)(r0 + lm) * TT + (t + 1)) * KIN + koff;
#pragma unroll
        for (int kit = 0; kit < KIT_IN; ++kit) {
          xa[2 * kit]     = *(const float4*)(xr + kit * 32);
          xa[2 * kit + 1] = *(const float4*)(xr + kit * 32 + 4);
        }
      }
    } else {
#pragma unroll
      for (int kit = 0; kit < KIT_IN; ++kit)
#pragma unroll
        for (int nt = 0; nt < 4; ++nt)
          acc[nt] = __builtin_amdgcn_mfma_f32_16x16x32_bf16(xf[kit], wih_f[kit][nt], acc[nt], 0, 0, 0);
    }

    // ---- 3) own-state poll + recurrence MFMAs ----
    if (t > 0) {
      const unsigned short* ph = S + ((size_t)(r0 + lm) * TT + (t - 1)) * HH
                                   + (size_t)w * (HH / NW) + lq * 8;
      frag8 hf[KIT_HH];
      poll256(hf, ph);
#pragma unroll
      for (int kit = 0; kit < KIT_HH; ++kit)
#pragma unroll
        for (int nt = 0; nt < 4; ++nt)
          acc[nt] = __builtin_amdgcn_mfma_f32_16x16x32_bf16(hf[kit], whh_f[kit][nt], acc[nt], 0, 0, 0);
    }

    // ---- 4) pass1: K-split partials to LDS (double-buffered) ----
    // C/D layout: col = lane&15, row = (lane>>4)*4 + reg  [verified m89/m91]
    float* pb = parts + (t & 1) * PBUF;
#pragma unroll
    for (int nt = 0; nt < 4; ++nt)
#pragma unroll
      for (int r = 0; r < 4; ++r)
        pb[((w * 4 + nt) * 16 + lq * 4 + r) * PSTR + lm] = acc[nt][r];
    __syncthreads();

    // ---- 5) pass2: reduce 8 K-chunks, tanh, pack 2 cols -> LDS stage ----
    unsigned int hb2 = 0;
#pragma unroll
    for (int j = 0; j < 2; ++j) {
      int c  = ecg * 2 + j;
      int nt = c >> 4;
      int lc = c & 15;
      float sm = 0.f;
#pragma unroll
      for (int w8 = 0; w8 < NW; ++w8)
        sm += pb[((w8 * 4 + nt) * 16 + erow) * PSTR + lc];
      float u = sm + bias2[j];
      float e = __expf(2.0f * u);               // tanh via exp, inf-safe:
      float hv = 1.0f - 2.0f / (e + 1.0f);      // finite, |hv|<=1, NEVER NaN
      hb2 |= (unsigned int)f2bf(hv) << (16 * j);
    }
    stage[erow * SSTR + ecg] = hb2;
    __syncthreads();

    // ---- 6) publish: 128 threads x one dwordx4 sc1 (16B, 8 cols each) ----
    if (tid < 128) {
      u32x4 v = *(const u32x4*)(stage + prow * SSTR + pc8 * 4);
      unsigned short* dst = S + ((size_t)(r0 + prow) * TT + t) * HH + j0 + pc8 * 8;
      st128_sc1((unsigned int*)dst, v);
    }
    // No third barrier: stage(t) readers (tid<128) pass barrier of t+1 only
    // after reading; parts[t&1] reuse at t+2 is ordered by the two barriers
    // of step t+1. Threads >=128 may run ahead into step t+1 — their polls
    // are the sync.

    // ---- 7) L1: tail-poll x(t+1) = h1[t+1] (L0 runs ahead; usually ready;
    // its RTT overlaps our own store-visibility window)
    if constexpr (!L0) {
      if (t + 1 < TT) {
        const unsigned short* px = (const unsigned short*)Xv
            + ((size_t)(r0 + lm) * TT + (t + 1)) * KIN + koff;
        poll256(xf, px);
      }
    }
  }
}

__global__ __launch_bounds__(THREADS, 1)
void rnn_fused(const float* x,
               const float* Wih0, const float* Whh0, const float* bih0, const float* bhh0,
               const float* Wih1, const float* Whh1, const float* bih1, const float* bhh1,
               unsigned short* h1seq, unsigned short* h2seq)
{
  __shared__ float parts[2 * PBUF];
  __shared__ unsigned int stage[16 * SSTR];
  const int wg = blockIdx.x;
  if (wg < GROUPS * WGS_PER_GROUP) {
    const int g = wg / WGS_PER_GROUP, s = wg % WGS_PER_GROUP;
    scan_body<DIN, true>(x, Wih0, Whh0, bih0, bhh0, h1seq, g, s, parts, stage);
  } else {
    const int wg2 = wg - GROUPS * WGS_PER_GROUP;
    const int g = wg2 / WGS_PER_GROUP, s = wg2 % WGS_PER_GROUP;
    scan_body<HH, false>(h1seq, Wih1, Whh1, bih1, bhh1, h2seq, g, s, parts, stage);
  }
}

// poison h1seq+h2seq with the sentinel every launch (stale non-sentinel data
// from a previous launch would be a false-positive for the data-poll).
__global__ void poison_kernel(uint4* __restrict__ p, int n4) {
  int i  = blockIdx.x * blockDim.x + threadIdx.x;
  int st = gridDim.x * blockDim.x;
  const uint4 v = make_uint4(SENT, SENT, SENT, SENT);
  for (; i < n4; i += st) p[i] = v;
}

// out[m][n] = h2seq[m][T-1] . Wfc[n] + bfc[n]
__global__ void fc_kernel(const unsigned short* __restrict__ h2seq,  // bf16
                          const float* __restrict__ Wfc,             // fp32
                          const float* __restrict__ bfc,             // fp32
                          float* __restrict__ out)                   // fp32
{
  int idx = blockIdx.x * blockDim.x + threadIdx.x;  // 32768 = 64*512
  int m = idx >> 9;
  int n = idx & 511;
  const unsigned short* hp = h2seq + ((size_t)m * TT + (TT - 1)) * HH;
  const float*          wp = Wfc + (size_t)n * HH;
  float acc = 0.f;
#pragma unroll 4
  for (int k = 0; k < HH; k += 4) {
    ushort4 hv = *(const ushort4*)(hp + k);
    float4  wv = *(const float4*)(wp + k);
    acc += bf2f(hv.x) * wv.x + bf2f(hv.y) * wv.y
         + bf2f(hv.z) * wv.z + bf2f(hv.w) * wv.w;
  }
  out[idx] = acc + bfc[n];
}

extern "C" void kernel_launch(void* const* d_in, const int* in_sizes, int n_in,
                              void* d_out, int out_size, void* d_ws, size_t ws_size,
                              hipStream_t stream)
{
  const float* x    = (const float*)d_in[0];
  const float* Wih0 = (const float*)d_in[1];
  const float* Whh0 = (const float*)d_in[2];
  const float* bih0 = (const float*)d_in[3];
  const float* bhh0 = (const float*)d_in[4];
  const float* Wih1 = (const float*)d_in[5];
  const float* Whh1 = (const float*)d_in[6];
  const float* bih1 = (const float*)d_in[7];
  const float* bhh1 = (const float*)d_in[8];
  const float* Wfc  = (const float*)d_in[9];
  const float* bfc  = (const float*)d_in[10];

  // ws: h1seq (64MB) | h2seq (64MB) — both write-once bf16 [B][T][H]
  unsigned char* ws = (unsigned char*)d_ws;
  unsigned short* h1seq = (unsigned short*)ws;
  unsigned short* h2seq = (unsigned short*)(ws + (size_t)BB * TT * HH * 2);

  // sentinel-poison both state arrays (128 MiB, ~25 us)
  poison_kernel<<<4096, 256, 0, stream>>>(
      (uint4*)ws, (int)(((size_t)BB * TT * HH * 2 * 2) / 16));

  // fused 2-layer pipelined scan: WGs 0..63 = layer 0, 64..127 = layer 1
  rnn_fused<<<2 * GROUPS * WGS_PER_GROUP, THREADS, 0, stream>>>(
      x, Wih0, Whh0, bih0, bhh0, Wih1, Whh1, bih1, bhh1, h1seq, h2seq);

  fc_kernel<<<(BB * DOUT) / 256, 256, 0, stream>>>(h2seq, Wfc, bfc, (float*)d_out);
}

// Round 5
// 1826.732 us; speedup vs baseline: 1.3227x; 1.0178x over previous
//
#include <hip/hip_runtime.h>
#include <stdint.h>

// Problem constants
#define BB   64
#define TT   512
#define DIN  512
#define HH   1024
#define DOUT 512

// 4 independent batch groups x 16 rows; per group 16 WGs each owning 64 cols;
// 8 waves/WG K-split (128 K each). Layer 1 runs concurrently (WGs 64..127).
//
// SYNC: data-is-the-flag. Producers store h as bf16 (sc1). Consumers spin on
// the DATA with a NaN sentinel: tanh output is finite |h|<=1, so f2bf never
// emits 0x7FFF; 0x7FFF7FFF is unreachable. State buffers are sentinel-
// poisoned each launch; every location is written exactly once; dword stores
// are atomic -> non-sentinel poll result IS the data.
//
// POLLS ARE FUSED (issue + s_waitcnt in ONE asm block). Round-2 lesson:
// split-phase polling (asm-output loads in flight across compiler-visible
// code) is UNSAFE — the allocator may spill/copy the in-flight destination
// registers before data lands.
//
// Round-5 model: the kernel sits near the COHERENT-FABRIC BYTE FLOOR —
// each step moves ~6 MB of device-coherent h-broadcast (L0: 16 WGs x 32KB,
// L1: 16 WGs x 64KB, x4 groups). Back-to-back spin retries re-read the
// full payload every RTT, amplifying this floor ~1.5-2.5x (RTT inflates
// until traffic = capacity). Fix: s_sleep-paced polling — first attempt
// immediate (fast path when data ready), then ~768cy sleep between
// attempts. Sleep costs no fabric bytes and frees the SIMD. Round-4's
// probe+confirm removed: the confirm was a full extra RTT on detect.
#define GROUPS        4
#define ROWS          16
#define WGS_PER_GROUP 16
#define NSLICE        64
#define THREADS       512
#define NW            8
#define PSTR          18            // LDS parts stride: uniform 2-way (free)
#define PBUF          (NW * 4 * 16 * PSTR)
#define SSTR          36            // stage stride (dwords)
#define SENT          0x7fff7fffu   // two NaN bf16 halves; unreachable output

typedef __attribute__((ext_vector_type(8))) short frag8;        // 8 x bf16
typedef __attribute__((ext_vector_type(4))) float f32x4;        // MFMA acc
typedef __attribute__((ext_vector_type(4))) unsigned int u32x4; // asm payload

union U4F8 { u32x4 u; frag8 f; };

__device__ __forceinline__ float bf2f(unsigned short u) {
  union { unsigned int i; float f; } v; v.i = ((unsigned int)u) << 16; return v.f;
}
__device__ __forceinline__ unsigned short f2bf(float f) {
  union { float f; unsigned int i; } v; v.f = f;
  unsigned int x = v.i;
  x += 0x7fffu + ((x >> 16) & 1u);   // RNE
  return (unsigned short)(x >> 16);
}
__device__ __forceinline__ frag8 ld8f32(const float* p) {
  frag8 r;
#pragma unroll
  for (int j = 0; j < 8; ++j) r[j] = (short)f2bf(p[j]);
  return r;
}

// ---- fused device-scope (sc1) polling load: 4 dwordx4 + ONE waitcnt inside
// a single asm block. "=&v" early-clobber REQUIRED.
__device__ __forceinline__ bool ldx4_poll(frag8 a[4], const unsigned short* p) {
  u32x4 t0, t1, t2, t3;
  asm volatile(
      "global_load_dwordx4 %0, %4, off sc1\n\t"
      "global_load_dwordx4 %1, %4, off offset:64 sc1\n\t"
      "global_load_dwordx4 %2, %4, off offset:128 sc1\n\t"
      "global_load_dwordx4 %3, %4, off offset:192 sc1\n\t"
      "s_waitcnt vmcnt(0)"
      : "=&v"(t0), "=&v"(t1), "=&v"(t2), "=&v"(t3)
      : "v"(p)
      : "memory");
  bool ok = (t0[0] != SENT) & (t0[1] != SENT) & (t0[2] != SENT) & (t0[3] != SENT)
          & (t1[0] != SENT) & (t1[1] != SENT) & (t1[2] != SENT) & (t1[3] != SENT)
          & (t2[0] != SENT) & (t2[1] != SENT) & (t2[2] != SENT) & (t2[3] != SENT)
          & (t3[0] != SENT) & (t3[1] != SENT) & (t3[2] != SENT) & (t3[3] != SENT);
  U4F8 u;
  u.u = t0; a[0] = u.f;  u.u = t1; a[1] = u.f;
  u.u = t2; a[2] = u.f;  u.u = t3; a[3] = u.f;
  return __ballot(ok) == ~0ull;
}
// paced poll: immediate first attempt (fast path when producer is ahead),
// then s_sleep(12) ~ 768 cy between attempts. Sleeping costs zero fabric
// traffic (vs back-to-back 4KB re-reads every RTT) — drives the coherent
// spin-read amplification toward 1x and lets the fabric decongest.
__device__ __forceinline__ void poll256(frag8 a[4], const unsigned short* p) {
  if (ldx4_poll(a, p)) return;
  for (;;) {
    __builtin_amdgcn_s_sleep(12);      // ~768 cycles, no memory traffic
    if (ldx4_poll(a, p)) return;
  }
}
__device__ __forceinline__ void st128_sc1(unsigned int* p, u32x4 v) {
  asm volatile("global_store_dwordx4 %0, %1, off sc1" :: "v"(p), "v"(v) : "memory");
}

// One RNN layer scan step-loop. L0: X = fp32 x (register-prefetched under
// the poll), state seq = h1seq. L1: X = bf16 h1seq (tail-polled), state
// seq = h2seq. S layout: [row][t][HH] bf16, write-once per location.
template<int KIN, bool L0>
__device__ void scan_body(const void* Xv,
                          const float* Wih, const float* Whh,
                          const float* bih, const float* bhh,
                          unsigned short* S,
                          int g, int s, float* parts, unsigned int* stage)
{
  constexpr int KIT_IN = KIN / (NW * 32);   // L0: 2, L1: 4
  constexpr int KIT_HH = HH  / (NW * 32);   // 4

  const int j0  = s * NSLICE;
  const int r0  = g * ROWS;
  const int tid = threadIdx.x;
  const int w   = tid >> 6;                 // wave 0..7 (K-split)
  const int l   = tid & 63;
  const int lm  = l & 15;
  const int lq  = l >> 4;

  // ---- preload weights to VGPR frags (fp32 -> bf16 once) ----
  // B-frag: lane holds W[n = j0+nt*16+lm][k = w*(K/8) + kit*32 + lq*8 .. +7]
  frag8 wih_f[KIT_IN][4];
  frag8 whh_f[KIT_HH][4];
#pragma unroll
  for (int kit = 0; kit < KIT_IN; ++kit)
#pragma unroll
    for (int nt = 0; nt < 4; ++nt) {
      int n = j0 + nt * 16 + lm;
      int k = w * (KIN / NW) + kit * 32 + lq * 8;
      wih_f[kit][nt] = ld8f32(Wih + (size_t)n * KIN + k);
    }
#pragma unroll
  for (int kit = 0; kit < KIT_HH; ++kit)
#pragma unroll
    for (int nt = 0; nt < 4; ++nt) {
      int n = j0 + nt * 16 + lm;
      int k = w * (HH / NW) + kit * 32 + lq * 8;
      whh_f[kit][nt] = ld8f32(Whh + (size_t)n * HH + k);
    }

  // pass2: thread -> (row = tid&15, 2 contiguous cols at (tid>>4)*2)
  const int erow = tid & 15;
  const int ecg  = tid >> 4;               // 0..31
  float bias2[2];
#pragma unroll
  for (int j = 0; j < 2; ++j) {
    int c = j0 + ecg * 2 + j;
    bias2[j] = bih[c] + bhh[c];
  }
  // publisher: thread < 128 -> (row = tid>>3, 8 cols at (tid&7)*8)
  const int prow = tid >> 3;
  const int pc8  = tid & 7;

  // per-lane A-frag source offset within a timestep row
  const size_t koff = (size_t)w * (KIN / NW) + (size_t)lq * 8;

  // ---- stage x(0) into registers ----
  float4 xa[2 * KIT_IN];                    // L0 fp32 prefetch
  frag8  xf[KIT_IN];                        // L1 polled bf16 frags
  if constexpr (L0) {
    const float* xr = (const float*)Xv + ((size_t)(r0 + lm) * TT + 0) * KIN + koff;
#pragma unroll
    for (int kit = 0; kit < KIT_IN; ++kit) {
      xa[2 * kit]     = *(const float4*)(xr + kit * 32);
      xa[2 * kit + 1] = *(const float4*)(xr + kit * 32 + 4);
    }
  } else {
    const unsigned short* px = (const unsigned short*)Xv
        + ((size_t)(r0 + lm) * TT + 0) * KIN + koff;
    poll256(xf, px);
  }

  for (int t = 0; t < TT; ++t) {
    f32x4 acc[4];
#pragma unroll
    for (int nt = 0; nt < 4; ++nt) acc[nt] = (f32x4){0.f, 0.f, 0.f, 0.f};

    // ---- 1) x-projection: register-only at step head ----
    if constexpr (L0) {
#pragma unroll
      for (int kit = 0; kit < KIT_IN; ++kit) {
        const float* f0 = (const float*)&xa[2 * kit];
        const float* f1 = (const float*)&xa[2 * kit + 1];
        frag8 a;
#pragma unroll
        for (int j = 0; j < 4; ++j) {
          a[j]     = (short)f2bf(f0[j]);
          a[4 + j] = (short)f2bf(f1[j]);
        }
#pragma unroll
        for (int nt = 0; nt < 4; ++nt)
          acc[nt] = __builtin_amdgcn_mfma_f32_16x16x32_bf16(a, wih_f[kit][nt], acc[nt], 0, 0, 0);
      }
      // ---- 2) issue x(t+1) prefetch BEFORE the poll: the poll's vmcnt(0)
      // drains it, so its HBM latency rides entirely under the spin.
      if (t + 1 < TT) {
        const float* xr = (const float*)Xv
            + ((size_t)(r0 + lm) * TT + (t + 1)) * KIN + koff;
#pragma unroll
        for (int kit = 0; kit < KIT_IN; ++kit) {
          xa[2 * kit]     = *(const float4*)(xr + kit * 32);
          xa[2 * kit + 1] = *(const float4*)(xr + kit * 32 + 4);
        }
      }
    } else {
#pragma unroll
      for (int kit = 0; kit < KIT_IN; ++kit)
#pragma unroll
        for (int nt = 0; nt < 4; ++nt)
          acc[nt] = __builtin_amdgcn_mfma_f32_16x16x32_bf16(xf[kit], wih_f[kit][nt], acc[nt], 0, 0, 0);
    }

    // ---- 3) own-state poll + recurrence MFMAs ----
    if (t > 0) {
      const unsigned short* ph = S + ((size_t)(r0 + lm) * TT + (t - 1)) * HH
                                   + (size_t)w * (HH / NW) + lq * 8;
      frag8 hf[KIT_HH];
      poll256(hf, ph);
#pragma unroll
      for (int kit = 0; kit < KIT_HH; ++kit)
#pragma unroll
        for (int nt = 0; nt < 4; ++nt)
          acc[nt] = __builtin_amdgcn_mfma_f32_16x16x32_bf16(hf[kit], whh_f[kit][nt], acc[nt], 0, 0, 0);
    }

    // ---- 4) pass1: K-split partials to LDS (double-buffered) ----
    // C/D layout: col = lane&15, row = (lane>>4)*4 + reg  [verified m89/m91]
    float* pb = parts + (t & 1) * PBUF;
#pragma unroll
    for (int nt = 0; nt < 4; ++nt)
#pragma unroll
      for (int r = 0; r < 4; ++r)
        pb[((w * 4 + nt) * 16 + lq * 4 + r) * PSTR + lm] = acc[nt][r];
    __syncthreads();

    // ---- 5) pass2: reduce 8 K-chunks, tanh, pack 2 cols -> LDS stage ----
    unsigned int hb2 = 0;
#pragma unroll
    for (int j = 0; j < 2; ++j) {
      int c  = ecg * 2 + j;
      int nt = c >> 4;
      int lc = c & 15;
      float sm = 0.f;
#pragma unroll
      for (int w8 = 0; w8 < NW; ++w8)
        sm += pb[((w8 * 4 + nt) * 16 + erow) * PSTR + lc];
      float u = sm + bias2[j];
      float e = __expf(2.0f * u);               // tanh via exp, inf-safe:
      float hv = 1.0f - 2.0f / (e + 1.0f);      // finite, |hv|<=1, NEVER NaN
      hb2 |= (unsigned int)f2bf(hv) << (16 * j);
    }
    stage[erow * SSTR + ecg] = hb2;
    __syncthreads();

    // ---- 6) publish: 128 threads x one dwordx4 sc1 (16B, 8 cols each) ----
    if (tid < 128) {
      u32x4 v = *(const u32x4*)(stage + prow * SSTR + pc8 * 4);
      unsigned short* dst = S + ((size_t)(r0 + prow) * TT + t) * HH + j0 + pc8 * 8;
      st128_sc1((unsigned int*)dst, v);
    }
    // No third barrier: stage(t) readers (tid<128) pass barrier #1 of step
    // t+1 only after reading; parts reuse at t+2 is ordered by t+1's two
    // barriers. Threads >=128 run ahead — their polls are the sync.

    // ---- 7) L1: tail-poll x(t+1) = h1[t+1] (L0 runs ahead; usually ready;
    // its RTT overlaps our own store-visibility window)
    if constexpr (!L0) {
      if (t + 1 < TT) {
        const unsigned short* px = (const unsigned short*)Xv
            + ((size_t)(r0 + lm) * TT + (t + 1)) * KIN + koff;
        poll256(xf, px);
      }
    }
  }
}

__global__ __launch_bounds__(THREADS, 1)
void rnn_fused(const float* x,
               const float* Wih0, const float* Whh0, const float* bih0, const float* bhh0,
               const float* Wih1, const float* Whh1, const float* bih1, const float* bhh1,
               unsigned short* h1seq, unsigned short* h2seq)
{
  __shared__ float parts[2 * PBUF];
  __shared__ unsigned int stage[16 * SSTR];
  const int wg = blockIdx.x;
  if (wg < GROUPS * WGS_PER_GROUP) {
    const int g = wg / WGS_PER_GROUP, s = wg % WGS_PER_GROUP;
    scan_body<DIN, true>(x, Wih0, Whh0, bih0, bhh0, h1seq, g, s, parts, stage);
  } else {
    const int wg2 = wg - GROUPS * WGS_PER_GROUP;
    const int g = wg2 / WGS_PER_GROUP, s = wg2 % WGS_PER_GROUP;
    scan_body<HH, false>(h1seq, Wih1, Whh1, bih1, bhh1, h2seq, g, s, parts, stage);
  }
}

// poison h1seq+h2seq with the sentinel every launch (stale non-sentinel data
// from a previous launch would be a false-positive for the data-poll).
__global__ void poison_kernel(uint4* __restrict__ p, int n4) {
  int i  = blockIdx.x * blockDim.x + threadIdx.x;
  int st = gridDim.x * blockDim.x;
  const uint4 v = make_uint4(SENT, SENT, SENT, SENT);
  for (; i < n4; i += st) p[i] = v;
}

// out[m][n] = h2seq[m][T-1] . Wfc[n] + bfc[n]
__global__ void fc_kernel(const unsigned short* __restrict__ h2seq,  // bf16
                          const float* __restrict__ Wfc,             // fp32
                          const float* __restrict__ bfc,             // fp32
                          float* __restrict__ out)                   // fp32
{
  int idx = blockIdx.x * blockDim.x + threadIdx.x;  // 32768 = 64*512
  int m = idx >> 9;
  int n = idx & 511;
  const unsigned short* hp = h2seq + ((size_t)m * TT + (TT - 1)) * HH;
  const float*          wp = Wfc + (size_t)n * HH;
  float acc = 0.f;
#pragma unroll 4
  for (int k = 0; k < HH; k += 4) {
    ushort4 hv = *(const ushort4*)(hp + k);
    float4  wv = *(const float4*)(wp + k);
    acc += bf2f(hv.x) * wv.x + bf2f(hv.y) * wv.y
         + bf2f(hv.z) * wv.z + bf2f(hv.w) * wv.w;
  }
  out[idx] = acc + bfc[n];
}

extern "C" void kernel_launch(void* const* d_in, const int* in_sizes, int n_in,
                              void* d_out, int out_size, void* d_ws, size_t ws_size,
                              hipStream_t stream)
{
  const float* x    = (const float*)d_in[0];
  const float* Wih0 = (const float*)d_in[1];
  const float* Whh0 = (const float*)d_in[2];
  const float* bih0 = (const float*)d_in[3];
  const float* bhh0 = (const float*)d_in[4];
  const float* Wih1 = (const float*)d_in[5];
  const float* Whh1 = (const float*)d_in[6];
  const float* bih1 = (const float*)d_in[7];
  const float* bhh1 = (const float*)d_in[8];
  const float* Wfc  = (const float*)d_in[9];
  const float* bfc  = (const float*)d_in[10];

  // ws: h1seq (64MB) | h2seq (64MB) — both write-once bf16 [B][T][H]
  unsigned char* ws = (unsigned char*)d_ws;
  unsigned short* h1seq = (unsigned short*)ws;
  unsigned short* h2seq = (unsigned short*)(ws + (size_t)BB * TT * HH * 2);

  // sentinel-poison both state arrays (128 MiB, ~25 us)
  poison_kernel<<<4096, 256, 0, stream>>>(
      (uint4*)ws, (int)(((size_t)BB * TT * HH * 2 * 2) / 16));

  // fused 2-layer pipelined scan: WGs 0..63 = layer 0, 64..127 = layer 1
  rnn_fused<<<2 * GROUPS * WGS_PER_GROUP, THREADS, 0, stream>>>(
      x, Wih0, Whh0, bih0, bhh0, Wih1, Whh1, bih1, bhh1, h1seq, h2seq);

  fc_kernel<<<(BB * DOUT) / 256, 256, 0, stream>>>(h2seq, Wfc, bfc, (float*)d_out);
}